// Round 4
// baseline (326.606 us; speedup 1.0000x reference)
//
#include <hip/hip_runtime.h>
#include <hip/hip_bf16.h>
#include <math.h>

typedef __bf16 bf16x8 __attribute__((ext_vector_type(8)));
typedef float f32x4 __attribute__((ext_vector_type(4)));
typedef unsigned short u16x4 __attribute__((ext_vector_type(4)));

#define AS1P const __attribute__((address_space(1))) void*
#define AS3P __attribute__((address_space(3))) void*

__device__ __forceinline__ float b2f(unsigned short h) {
    unsigned int u = ((unsigned int)h) << 16;
    return __builtin_bit_cast(float, u);
}
__device__ __forceinline__ unsigned short f2b(float f) {
    unsigned int u = __builtin_bit_cast(unsigned int, f);
    u += 0x7FFFu + ((u >> 16) & 1u);
    return (unsigned short)(u >> 16);
}
__device__ __forceinline__ float silu(float c) {
    return c * __builtin_amdgcn_rcpf(1.0f + __expf(-c));
}

// ---------------- tiled transpose + bf16 convert: dst[C][R] <- src[R][C]
__global__ __launch_bounds__(256) void k_convT(const float* __restrict__ src,
                                               unsigned short* __restrict__ dst,
                                               int R, int C) {
    __shared__ float tile[32][33];
    int tx = threadIdx.x, ty = threadIdx.y;
    int r0 = blockIdx.y << 5, c0 = blockIdx.x << 5;
#pragma unroll
    for (int i = 0; i < 4; ++i)
        tile[ty + 8 * i][tx] = src[(long long)(r0 + ty + 8 * i) * C + c0 + tx];
    __syncthreads();
#pragma unroll
    for (int i = 0; i < 4; ++i)
        dst[(long long)(c0 + ty + 8 * i) * R + r0 + tx] = f2b(tile[tx][ty + 8 * i]);
}

// ---------------- LayerNorm: x[16384][768] f32 -> xn bf16
__global__ __launch_bounds__(256) void k_ln(const float* __restrict__ x,
                                            const float* __restrict__ g,
                                            const float* __restrict__ b,
                                            unsigned short* __restrict__ xn) {
    int row = blockIdx.x;
    int t = threadIdx.x;
    const float* xr = x + (long long)row * 768;
    float v0 = xr[t], v1 = xr[t + 256], v2 = xr[t + 512];
    float s = v0 + v1 + v2;
    float q = v0 * v0 + v1 * v1 + v2 * v2;
#pragma unroll
    for (int off = 32; off > 0; off >>= 1) {
        s += __shfl_xor(s, off);
        q += __shfl_xor(q, off);
    }
    __shared__ float ss[4], sq[4];
    int w = t >> 6;
    if ((t & 63) == 0) { ss[w] = s; sq[w] = q; }
    __syncthreads();
    float S_ = ss[0] + ss[1] + ss[2] + ss[3];
    float Q_ = sq[0] + sq[1] + sq[2] + sq[3];
    float mu = S_ * (1.0f / 768.0f);
    float var = Q_ * (1.0f / 768.0f) - mu * mu;
    float rs = rsqrtf(var + 1e-5f);
    unsigned short* xo = xn + (long long)row * 768;
    xo[t]       = f2b((v0 - mu) * rs * g[t]       + b[t]);
    xo[t + 256] = f2b((v1 - mu) * rs * g[t + 256] + b[t + 256]);
    xo[t + 512] = f2b((v2 - mu) * rs * g[t + 512] + b[t + 512]);
}

// ---------------- RoPE + per-head affine
__global__ __launch_bounds__(128) void k_rope(const unsigned short* __restrict__ bS,
                                              const float* __restrict__ gqk,
                                              const float* __restrict__ bqk,
                                              unsigned short* __restrict__ q,
                                              unsigned short* __restrict__ k) {
    int row = blockIdx.x;
    int l = row & 511;
    int s = threadIdx.x;
    int j = s & 63;
    int partner = s ^ 64;
    float b0 = b2f(bS[(long long)row * 128 + s]);
    float bp = b2f(bS[(long long)row * 128 + partner]);
    float invf = __expf((float)j * -0.14391156831f);
    float th = (float)l * invf;
    float sn, cs;
    __sincosf(th, &sn, &cs);
    float sign = (s < 64) ? -1.0f : 1.0f;
    float preq  = b0 * gqk[s]           + bqk[s];
    float preqp = bp * gqk[partner]     + bqk[partner];
    q[(long long)row * 128 + s] = f2b(preq * cs + sign * preqp * sn);
    float prek  = b0 * gqk[128 + s]       + bqk[128 + s];
    float prekp = bp * gqk[128 + partner] + bqk[128 + partner];
    k[(long long)row * 128 + s] = f2b(prek * cs + sign * prekp * sn);
}

// ================= 128^2 2-phase kernel (kept for QK (EPI=1) and bS (EPI=5))
template <int EPI, bool SWAP, bool SWZ>
__global__ __launch_bounds__(256) void k_gemm(const unsigned short* __restrict__ A,
                                              const unsigned short* __restrict__ B,
                                              int K, long long strideA, long long strideB,
                                              void* p0, const void* p1, const void* p2,
                                              const void* p3) {
    __shared__ __align__(16) unsigned short As[128 * 64];
    __shared__ __align__(16) unsigned short Bs[128 * 64];
    int t = threadIdx.x;
    int w = t >> 6, lane = t & 63;
    int wr = w >> 1, wc = w & 1;
    int bx = blockIdx.x, by = blockIdx.y, bz = blockIdx.z;
    if constexpr (SWZ) {
        int gx = gridDim.x;
        int nb = gx * gridDim.y;
        int bid = by * gx + bx;
        int s = (bid & 7) * (nb >> 3) + (bid >> 3);
        bx = s % gx;
        by = s / gx;
    }
    const unsigned short* Ab = A + bz * strideA + (long long)by * 128 * K;
    const unsigned short* Bb = B + bz * strideB + (long long)bx * 128 * K;

    f32x4 acc[4][4];
#pragma unroll
    for (int m = 0; m < 4; ++m)
#pragma unroll
        for (int n = 0; n < 4; ++n) acc[m][n] = (f32x4){0.f, 0.f, 0.f, 0.f};

    int rowA = (w << 3) + (lane >> 3);
    int colA = (lane & 7) << 3;

    for (int k0 = 0; k0 < K; k0 += 64) {
#pragma unroll
        for (int i = 0; i < 4; ++i) {
            int r = (i << 5) + rowA;
            __builtin_amdgcn_global_load_lds(
                (AS1P)(Ab + (long long)r * K + k0 + colA),
                (AS3P)(&As[(i << 11) + (w << 9)]), 16, 0, 0);
            __builtin_amdgcn_global_load_lds(
                (AS1P)(Bb + (long long)r * K + k0 + colA),
                (AS3P)(&Bs[(i << 11) + (w << 9)]), 16, 0, 0);
        }
        __syncthreads();
#pragma unroll
        for (int ks = 0; ks < 2; ++ks) {
            bf16x8 af[4], bfr[4];
#pragma unroll
            for (int m = 0; m < 4; ++m)
                af[m] = *(const bf16x8*)&As[((wr << 6) + (m << 4) + (lane & 15)) * 64 +
                                            (ks << 5) + ((lane >> 4) << 3)];
#pragma unroll
            for (int n = 0; n < 4; ++n)
                bfr[n] = *(const bf16x8*)&Bs[((wc << 6) + (n << 4) + (lane & 15)) * 64 +
                                             (ks << 5) + ((lane >> 4) << 3)];
#pragma unroll
            for (int m = 0; m < 4; ++m)
#pragma unroll
                for (int n = 0; n < 4; ++n) {
                    if constexpr (SWAP)
                        acc[m][n] = __builtin_amdgcn_mfma_f32_16x16x32_bf16(bfr[n], af[m],
                                                                            acc[m][n], 0, 0, 0);
                    else
                        acc[m][n] = __builtin_amdgcn_mfma_f32_16x16x32_bf16(af[m], bfr[n],
                                                                            acc[m][n], 0, 0, 0);
                }
        }
        __syncthreads();
    }

    int c15 = lane & 15, qq = lane >> 4;
    int rowb = (by << 7) + (wr << 6) + c15;
    int colb = (bx << 7) + (wc << 6) + (qq << 2);
#pragma unroll
    for (int m = 0; m < 4; ++m) {
#pragma unroll
        for (int n = 0; n < 4; ++n) {
            int grow = rowb + (m << 4);
            int gcol = colb + (n << 4);
            f32x4 a = acc[m][n];
            if constexpr (EPI == 5) {
                f32x4 bb = *(const f32x4*)((const float*)p3 + gcol);
                u16x4 o;
#pragma unroll
                for (int i = 0; i < 4; ++i) o[i] = f2b(silu(a[i] + bb[i]));
                *(u16x4*)((unsigned short*)p0 + (long long)grow * 128 + gcol) = o;
            } else {  // EPI == 1 : P = relu^2(qk/L + bias)
                const float* wrel = (const float*)p1;
                int base = gcol - grow + 511;
                u16x4 o;
#pragma unroll
                for (int i = 0; i < 4; ++i) {
                    float val = a[i] * (1.0f / 512.0f) + wrel[base + i];
                    val = fmaxf(val, 0.0f);
                    o[i] = f2b(val * val);
                }
                *(u16x4*)((unsigned short*)p0 +
                          ((long long)(bz * 512 + grow)) * 512 + gcol) = o;
            }
        }
    }
}

// ================= 256x256 ring-pipelined kernel: BK=32, 4 LDS buffers,
// counted vmcnt (never drains <8 in steady state), 32 MFMA per barrier.
__device__ __forceinline__ bf16x8 ldsread(const unsigned short* p) {
    bf16x8 r;
    unsigned int off =
        (unsigned int)(unsigned long long)(__attribute__((address_space(3))) const void*)p;
    asm volatile("ds_read_b128 %0, %1" : "=v"(r) : "v"(off));
    return r;
}

// stage one 256x32 bf16 tile (16KB) with 512 threads: 2 global_load_lds each
__device__ __forceinline__ void stage_tile(const unsigned short* __restrict__ g, int ldk,
                                           unsigned short* lds, int t) {
    int row = t >> 2;
    int colb = (t & 3) << 4;
    __builtin_amdgcn_global_load_lds(
        (AS1P)((const char*)(g + (long long)row * ldk) + colb),
        (AS3P)((char*)lds + t * 16), 16, 0, 0);
    __builtin_amdgcn_global_load_lds(
        (AS1P)((const char*)(g + (long long)(row + 128) * ldk) + colb),
        (AS3P)((char*)lds + 8192 + t * 16), 16, 0, 0);
}

// EPI: 0=u(silu+uv_b)  4=vT(silu, transposed, SWAP=false)  2=gated(PV*u)  3=out f32(+o_b+x)
template <int EPI, bool SWAP, bool SWZ, int NT>
__global__ __launch_bounds__(512, 2) void k_pipe(const unsigned short* __restrict__ A,
                                                 const unsigned short* __restrict__ B,
                                                 long long strideA, long long strideB,
                                                 void* p0, const void* p1, const void* p2,
                                                 const void* p3) {
    constexpr int K = NT * 32;
    __shared__ __align__(16) unsigned short As[4][256 * 32];
    __shared__ __align__(16) unsigned short Bs[4][256 * 32];
    int t = threadIdx.x;
    int w = t >> 6, lane = t & 63;
    int wr = w >> 2, wc = w & 3;
    int c15 = lane & 15, qq = lane >> 4;
    int bx = blockIdx.x, by = blockIdx.y, bz = blockIdx.z;
    if constexpr (SWZ) {
        int gx = gridDim.x;
        int nb = gx * gridDim.y;
        int bid = by * gx + bx;
        int s = (bid & 7) * (nb >> 3) + (bid >> 3);
        bx = s % gx;
        by = s / gx;
    }
    const unsigned short* Ab = A + bz * strideA + (long long)by * 256 * K;
    const unsigned short* Bb = B + bz * strideB + (long long)bx * 256 * K;

    f32x4 acc[8][4];
#pragma unroll
    for (int m = 0; m < 8; ++m)
#pragma unroll
        for (int n = 0; n < 4; ++n) acc[m][n] = (f32x4){0.f, 0.f, 0.f, 0.f};

    // prologue: stage tiles 0,1,2 into ring slots 0,1,2 (12 loads/thread)
#pragma unroll
    for (int p = 0; p < 3; ++p) {
        stage_tile(Ab + p * 32, K, &As[p][0], t);
        stage_tile(Bb + p * 32, K, &Bs[p][0], t);
    }

    for (int kt = 0; kt < NT; ++kt) {
        // wait: tile kt resident; tiles kt+1,kt+2 may remain in flight
        if (kt <= NT - 3)
            asm volatile("s_waitcnt vmcnt(8)" ::: "memory");
        else if (kt == NT - 2)
            asm volatile("s_waitcnt vmcnt(4)" ::: "memory");
        else
            asm volatile("s_waitcnt vmcnt(0)" ::: "memory");
        __builtin_amdgcn_s_barrier();          // all waves: tile kt ready, slot kt-1 free
        __builtin_amdgcn_sched_barrier(0);
        if (kt + 3 < NT) {                     // stage tile kt+3 into freed slot
            stage_tile(Ab + (long long)(kt + 3) * 32, K, &As[(kt + 3) & 3][0], t);
            stage_tile(Bb + (long long)(kt + 3) * 32, K, &Bs[(kt + 3) & 3][0], t);
        }
        const unsigned short* At = &As[kt & 3][0];
        const unsigned short* Bt = &Bs[kt & 3][0];
        bf16x8 bfr[4], af[8];
#pragma unroll
        for (int n = 0; n < 4; ++n)
            bfr[n] = ldsread(Bt + ((wc << 6) + (n << 4) + c15) * 32 + (qq << 3));
#pragma unroll
        for (int m = 0; m < 8; ++m)
            af[m] = ldsread(At + ((wr << 7) + (m << 4) + c15) * 32 + (qq << 3));
        asm volatile("s_waitcnt lgkmcnt(0)" ::: "memory");
        __builtin_amdgcn_sched_barrier(0);
        __builtin_amdgcn_s_setprio(1);
#pragma unroll
        for (int m = 0; m < 8; ++m)
#pragma unroll
            for (int n = 0; n < 4; ++n) {
                if constexpr (SWAP)
                    acc[m][n] = __builtin_amdgcn_mfma_f32_16x16x32_bf16(bfr[n], af[m],
                                                                        acc[m][n], 0, 0, 0);
                else
                    acc[m][n] = __builtin_amdgcn_mfma_f32_16x16x32_bf16(af[m], bfr[n],
                                                                        acc[m][n], 0, 0, 0);
            }
        __builtin_amdgcn_s_setprio(0);
    }

    if constexpr (SWAP) {
        int rowb = by * 256 + wr * 128 + c15;
        int colb = bx * 256 + wc * 64 + (qq << 2);
#pragma unroll
        for (int m = 0; m < 8; ++m) {
#pragma unroll
            for (int n = 0; n < 4; ++n) {
                int R = rowb + m * 16;
                int C = colb + n * 16;
                f32x4 a = acc[m][n];
                if constexpr (EPI == 0) {
                    f32x4 bb = *(const f32x4*)((const float*)p3 + C);
                    u16x4 o;
#pragma unroll
                    for (int i = 0; i < 4; ++i) o[i] = f2b(silu(a[i] + bb[i]));
                    *(u16x4*)((unsigned short*)p0 + (long long)R * 1536 + C) = o;
                } else if constexpr (EPI == 2) {
                    long long idx = ((long long)(bz * 512 + R)) * 1536 + C;
                    u16x4 uu = *(const u16x4*)((const unsigned short*)p1 + idx);
                    u16x4 o;
#pragma unroll
                    for (int i = 0; i < 4; ++i) o[i] = f2b(a[i] * b2f(uu[i]));
                    *(u16x4*)((unsigned short*)p0 + idx) = o;
                } else {  // EPI == 3
                    long long idx = (long long)R * 768 + C;
                    f32x4 xv = *(const f32x4*)((const float*)p2 + idx);
                    f32x4 ob = *(const f32x4*)((const float*)p1 + C);
                    f32x4 o;
#pragma unroll
                    for (int i = 0; i < 4; ++i) o[i] = a[i] + ob[i] + xv[i];
                    *(f32x4*)((float*)p0 + idx) = o;
                }
            }
        }
    } else {  // EPI == 4 : vT
        int rowb = by * 256 + wr * 128 + (qq << 2);
        int colb = bx * 256 + wc * 64 + c15;
#pragma unroll
        for (int m = 0; m < 8; ++m) {
#pragma unroll
            for (int n = 0; n < 4; ++n) {
                int grow = rowb + m * 16;
                int e = colb + n * 16;
                float bias = ((const float*)p3)[1536 + e];
                f32x4 a = acc[m][n];
                u16x4 o;
#pragma unroll
                for (int i = 0; i < 4; ++i) o[i] = f2b(silu(a[i] + bias));
                int bb2 = grow >> 9, mm = grow & 511;
                *(u16x4*)((unsigned short*)p0 + ((long long)bb2 * 1536 + e) * 512 + mm) = o;
            }
        }
    }
}

extern "C" void kernel_launch(void* const* d_in, const int* in_sizes, int n_in,
                              void* d_out, int out_size, void* d_ws, size_t ws_size,
                              hipStream_t stream) {
    const float* x     = (const float*)d_in[0];
    const float* ln_g  = (const float*)d_in[1];
    const float* ln_b  = (const float*)d_in[2];
    const float* uv_W  = (const float*)d_in[3];
    const float* uv_b  = (const float*)d_in[4];
    const float* g_qk  = (const float*)d_in[5];
    const float* b_qk  = (const float*)d_in[6];
    const float* w_rel = (const float*)d_in[7];
    const float* o_W   = (const float*)d_in[8];
    const float* o_b   = (const float*)d_in[9];
    float* out = (float*)d_out;

    char* ws = (char*)d_ws;
    size_t off = 0;
    auto alloc = [&](size_t bytes) {
        void* p = ws + off;
        off += (bytes + 255) & ~(size_t)255;
        return p;
    };
    unsigned short* uvWT = (unsigned short*)alloc(3200ll * 768 * 2);
    unsigned short* oWT  = (unsigned short*)alloc(768ll * 1536 * 2);
    unsigned short* xn   = (unsigned short*)alloc(16384ll * 768 * 2);
    unsigned short* u    = (unsigned short*)alloc(16384ll * 1536 * 2);
    unsigned short* vT   = (unsigned short*)alloc(32ll * 1536 * 512 * 2);
    unsigned short* bS   = (unsigned short*)alloc(16384ll * 128 * 2);
    unsigned short* q    = (unsigned short*)alloc(32ll * 512 * 128 * 2);
    unsigned short* k    = (unsigned short*)alloc(32ll * 512 * 128 * 2);
    unsigned short* P     = xn;  // alias: xn dead after GEMM1 trio
    unsigned short* gated = u;   // alias: same-thread read-then-write

    k_convT<<<dim3(100, 24), dim3(32, 8), 0, stream>>>(uv_W, uvWT, 768, 3200);
    k_convT<<<dim3(24, 48), dim3(32, 8), 0, stream>>>(o_W, oWT, 1536, 768);
    k_ln<<<16384, 256, 0, stream>>>(x, ln_g, ln_b, xn);
    // GEMM1: u | vT | bS   (K=768 -> NT=24)
    k_pipe<0, true, true, 24><<<dim3(6, 64), 512, 0, stream>>>(
        xn, uvWT, 0, 0, (void*)u, nullptr, nullptr, (const void*)uv_b);
    k_pipe<4, false, true, 24><<<dim3(6, 64), 512, 0, stream>>>(
        xn, uvWT + 1536ll * 768, 0, 0, (void*)vT, nullptr, nullptr, (const void*)uv_b);
    k_gemm<5, true, true><<<dim3(1, 128), 256, 0, stream>>>(
        xn, uvWT + 3072ll * 768, 768, 0, 0, (void*)bS, nullptr, nullptr,
        (const void*)(uv_b + 3072));
    k_rope<<<16384, 128, 0, stream>>>(bS, g_qk, b_qk, q, k);
    // QK^T -> P
    k_gemm<1, true, false><<<dim3(4, 4, 32), 256, 0, stream>>>(
        q, k, 128, 512ll * 128, 512ll * 128, (void*)P, (const void*)w_rel, nullptr, nullptr);
    // PV gated by u   (K=512 -> NT=16)
    k_pipe<2, true, false, 16><<<dim3(6, 2, 32), 512, 0, stream>>>(
        P, vT, 512ll * 512, 1536ll * 512, (void*)gated, (const void*)u, nullptr, nullptr);
    // out = gated @ oWT^T + o_b + x   (K=1536 -> NT=48)
    k_pipe<3, true, true, 48><<<dim3(3, 64), 512, 0, stream>>>(
        gated, oWT, 0, 0, (void*)out, (const void*)o_b, (const void*)x, nullptr);
}

// Round 5
// 300.519 us; speedup vs baseline: 1.0868x; 1.0868x over previous
//
#include <hip/hip_runtime.h>
#include <hip/hip_bf16.h>
#include <math.h>

typedef __bf16 bf16x8 __attribute__((ext_vector_type(8)));
typedef float f32x4 __attribute__((ext_vector_type(4)));
typedef unsigned short u16x4 __attribute__((ext_vector_type(4)));

#define AS1P const __attribute__((address_space(1))) void*
#define AS3P __attribute__((address_space(3))) void*

__device__ __forceinline__ float b2f(unsigned short h) {
    unsigned int u = ((unsigned int)h) << 16;
    return __builtin_bit_cast(float, u);
}
__device__ __forceinline__ unsigned short f2b(float f) {
    unsigned int u = __builtin_bit_cast(unsigned int, f);
    u += 0x7FFFu + ((u >> 16) & 1u);
    return (unsigned short)(u >> 16);
}
__device__ __forceinline__ float silu(float c) {
    return c * __builtin_amdgcn_rcpf(1.0f + __expf(-c));
}

// ---------------- tiled transpose + bf16 convert
__global__ __launch_bounds__(256) void k_convT(const float* __restrict__ src,
                                               unsigned short* __restrict__ dst,
                                               int R, int C) {
    __shared__ float tile[32][33];
    int tx = threadIdx.x, ty = threadIdx.y;
    int r0 = blockIdx.y << 5, c0 = blockIdx.x << 5;
#pragma unroll
    for (int i = 0; i < 4; ++i)
        tile[ty + 8 * i][tx] = src[(long long)(r0 + ty + 8 * i) * C + c0 + tx];
    __syncthreads();
#pragma unroll
    for (int i = 0; i < 4; ++i)
        dst[(long long)(c0 + ty + 8 * i) * R + r0 + tx] = f2b(tile[tx][ty + 8 * i]);
}

// ---------------- LayerNorm
__global__ __launch_bounds__(256) void k_ln(const float* __restrict__ x,
                                            const float* __restrict__ g,
                                            const float* __restrict__ b,
                                            unsigned short* __restrict__ xn) {
    int row = blockIdx.x;
    int t = threadIdx.x;
    const float* xr = x + (long long)row * 768;
    float v0 = xr[t], v1 = xr[t + 256], v2 = xr[t + 512];
    float s = v0 + v1 + v2;
    float q = v0 * v0 + v1 * v1 + v2 * v2;
#pragma unroll
    for (int off = 32; off > 0; off >>= 1) {
        s += __shfl_xor(s, off);
        q += __shfl_xor(q, off);
    }
    __shared__ float ss[4], sq[4];
    int w = t >> 6;
    if ((t & 63) == 0) { ss[w] = s; sq[w] = q; }
    __syncthreads();
    float S_ = ss[0] + ss[1] + ss[2] + ss[3];
    float Q_ = sq[0] + sq[1] + sq[2] + sq[3];
    float mu = S_ * (1.0f / 768.0f);
    float var = Q_ * (1.0f / 768.0f) - mu * mu;
    float rs = rsqrtf(var + 1e-5f);
    unsigned short* xo = xn + (long long)row * 768;
    xo[t]       = f2b((v0 - mu) * rs * g[t]       + b[t]);
    xo[t + 256] = f2b((v1 - mu) * rs * g[t + 256] + b[t + 256]);
    xo[t + 512] = f2b((v2 - mu) * rs * g[t + 512] + b[t + 512]);
}

// ---------------- RoPE + per-head affine
__global__ __launch_bounds__(128) void k_rope(const unsigned short* __restrict__ bS,
                                              const float* __restrict__ gqk,
                                              const float* __restrict__ bqk,
                                              unsigned short* __restrict__ q,
                                              unsigned short* __restrict__ k) {
    int row = blockIdx.x;
    int l = row & 511;
    int s = threadIdx.x;
    int j = s & 63;
    int partner = s ^ 64;
    float b0 = b2f(bS[(long long)row * 128 + s]);
    float bp = b2f(bS[(long long)row * 128 + partner]);
    float invf = __expf((float)j * -0.14391156831f);
    float th = (float)l * invf;
    float sn, cs;
    __sincosf(th, &sn, &cs);
    float sign = (s < 64) ? -1.0f : 1.0f;
    float preq  = b0 * gqk[s]           + bqk[s];
    float preqp = bp * gqk[partner]     + bqk[partner];
    q[(long long)row * 128 + s] = f2b(preq * cs + sign * preqp * sn);
    float prek  = b0 * gqk[128 + s]       + bqk[128 + s];
    float prekp = bp * gqk[128 + partner] + bqk[128 + partner];
    k[(long long)row * 128 + s] = f2b(prek * cs + sign * prekp * sn);
}

// ================= 128^2 2-phase kernel (QK only: P = relu^2(qk/L + bias))
__global__ __launch_bounds__(256) void k_qk(const unsigned short* __restrict__ A,
                                            const unsigned short* __restrict__ B,
                                            const float* __restrict__ wrel,
                                            unsigned short* __restrict__ P) {
    __shared__ __align__(16) unsigned short As[128 * 64];
    __shared__ __align__(16) unsigned short Bs[128 * 64];
    int t = threadIdx.x;
    int w = t >> 6, lane = t & 63;
    int wr = w >> 1, wc = w & 1;
    int bx = blockIdx.x, by = blockIdx.y, bz = blockIdx.z;
    const unsigned short* Ab = A + (long long)bz * 512 * 128 + (long long)by * 128 * 128;
    const unsigned short* Bb = B + (long long)bz * 512 * 128 + (long long)bx * 128 * 128;

    f32x4 acc[4][4];
#pragma unroll
    for (int m = 0; m < 4; ++m)
#pragma unroll
        for (int n = 0; n < 4; ++n) acc[m][n] = (f32x4){0.f, 0.f, 0.f, 0.f};

    int rowA = (w << 3) + (lane >> 3);
    int colA = (lane & 7) << 3;

    for (int k0 = 0; k0 < 128; k0 += 64) {
#pragma unroll
        for (int i = 0; i < 4; ++i) {
            int r = (i << 5) + rowA;
            __builtin_amdgcn_global_load_lds(
                (AS1P)(Ab + (long long)r * 128 + k0 + colA),
                (AS3P)(&As[(i << 11) + (w << 9)]), 16, 0, 0);
            __builtin_amdgcn_global_load_lds(
                (AS1P)(Bb + (long long)r * 128 + k0 + colA),
                (AS3P)(&Bs[(i << 11) + (w << 9)]), 16, 0, 0);
        }
        __syncthreads();
#pragma unroll
        for (int ks = 0; ks < 2; ++ks) {
            bf16x8 af[4], bfr[4];
#pragma unroll
            for (int m = 0; m < 4; ++m)
                af[m] = *(const bf16x8*)&As[((wr << 6) + (m << 4) + (lane & 15)) * 64 +
                                            (ks << 5) + ((lane >> 4) << 3)];
#pragma unroll
            for (int n = 0; n < 4; ++n)
                bfr[n] = *(const bf16x8*)&Bs[((wc << 6) + (n << 4) + (lane & 15)) * 64 +
                                             (ks << 5) + ((lane >> 4) << 3)];
#pragma unroll
            for (int m = 0; m < 4; ++m)
#pragma unroll
                for (int n = 0; n < 4; ++n)
                    acc[m][n] = __builtin_amdgcn_mfma_f32_16x16x32_bf16(bfr[n], af[m],
                                                                        acc[m][n], 0, 0, 0);
        }
        __syncthreads();
    }

    int c15 = lane & 15, qq = lane >> 4;
    int rowb = (by << 7) + (wr << 6) + c15;
    int colb = (bx << 7) + (wc << 6) + (qq << 2);
#pragma unroll
    for (int m = 0; m < 4; ++m) {
#pragma unroll
        for (int n = 0; n < 4; ++n) {
            int grow = rowb + (m << 4);
            int gcol = colb + (n << 4);
            f32x4 a = acc[m][n];
            int base = gcol - grow + 511;
            u16x4 o;
#pragma unroll
            for (int i = 0; i < 4; ++i) {
                float val = a[i] * (1.0f / 512.0f) + wrel[base + i];
                val = fmaxf(val, 0.0f);
                o[i] = f2b(val * val);
            }
            *(u16x4*)(P + ((long long)(bz * 512 + grow)) * 512 + gcol) = o;
        }
    }
}

// ================= 128x256 ring kernel: BK=32, 2 slots, counted vmcnt(6),
// granule swizzle g^=(row>>1)&3 (involution on src + ds_read). 2 blocks/CU.
__device__ __forceinline__ bf16x8 ldsread(const unsigned short* p) {
    bf16x8 r;
    unsigned int off =
        (unsigned int)(unsigned long long)(__attribute__((address_space(3))) const void*)p;
    asm volatile("ds_read_b128 %0, %1" : "=v"(r) : "v"(off));
    return r;
}
__device__ __forceinline__ bf16x8 frag32(const unsigned short* tile, int r, int qq) {
    return ldsread(tile + r * 32 + ((qq ^ ((r >> 1) & 3)) << 3));
}
template <int ROWS, int K>
__device__ __forceinline__ void stage_t(const unsigned short* __restrict__ g,
                                        unsigned short* lds, int t) {
#pragma unroll
    for (int i = 0; i < ROWS / 64; ++i) {
        int slot = t + (i << 8);
        int row = slot >> 2;
        int gs = (slot & 3) ^ ((row >> 1) & 3);
        __builtin_amdgcn_global_load_lds(
            (AS1P)(g + (long long)row * K + (gs << 3)),
            (AS3P)(lds + slot * 8), 16, 0, 0);
    }
}

template <bool SWAP, int NT>
__device__ __forceinline__ void ring_kloop(const unsigned short* __restrict__ Ab,
                                           const unsigned short* __restrict__ Bb,
                                           unsigned short* As0, unsigned short* As1,
                                           unsigned short* Bs0, unsigned short* Bs1,
                                           f32x4 (&acc)[8][4], int t, int wc, int c15, int qq) {
    constexpr int K = NT * 32;
    // prologue: stage tiles 0,1
    stage_t<128, K>(Ab, As0, t);
    stage_t<256, K>(Bb, Bs0, t);
    stage_t<128, K>(Ab + 32, As1, t);
    stage_t<256, K>(Bb + 32, Bs1, t);
    for (int kt = 0; kt < NT; ++kt) {
        if (kt < NT - 1)
            asm volatile("s_waitcnt vmcnt(6)" ::: "memory");
        else
            asm volatile("s_waitcnt vmcnt(0)" ::: "memory");
        __builtin_amdgcn_s_barrier();  // all waves' tile-kt loads landed
        __builtin_amdgcn_sched_barrier(0);
        const unsigned short* At = (kt & 1) ? As1 : As0;
        const unsigned short* Bt = (kt & 1) ? Bs1 : Bs0;
        bf16x8 af[8], bfr[4];
#pragma unroll
        for (int n = 0; n < 4; ++n) bfr[n] = frag32(Bt, wc * 64 + n * 16 + c15, qq);
#pragma unroll
        for (int m = 0; m < 8; ++m) af[m] = frag32(At, m * 16 + c15, qq);
        asm volatile("s_waitcnt lgkmcnt(0)" ::: "memory");
        __builtin_amdgcn_sched_barrier(0);
        __builtin_amdgcn_s_barrier();  // all waves done reading slot kt&1
        if (kt + 2 < NT) {             // refill the just-freed slot ((kt+2)&1 == kt&1)
            unsigned short* Asn = (kt & 1) ? As1 : As0;
            unsigned short* Bsn = (kt & 1) ? Bs1 : Bs0;
            stage_t<128, K>(Ab + (long long)(kt + 2) * 32, Asn, t);
            stage_t<256, K>(Bb + (long long)(kt + 2) * 32, Bsn, t);
        }
        __builtin_amdgcn_s_setprio(1);
#pragma unroll
        for (int m = 0; m < 8; ++m)
#pragma unroll
            for (int n = 0; n < 4; ++n) {
                if constexpr (SWAP)
                    acc[m][n] = __builtin_amdgcn_mfma_f32_16x16x32_bf16(bfr[n], af[m],
                                                                        acc[m][n], 0, 0, 0);
                else
                    acc[m][n] = __builtin_amdgcn_mfma_f32_16x16x32_bf16(af[m], bfr[n],
                                                                        acc[m][n], 0, 0, 0);
            }
        __builtin_amdgcn_s_setprio(0);
    }
}

// EPI: 10 = UV merged (u | vT | bS by bx)   2 = gated(PV*u)   3 = out f32(+o_b+x)
template <int EPI, bool SWZ, int NT>
__global__ __launch_bounds__(256, 2) void k_ring(const unsigned short* __restrict__ A,
                                                 const unsigned short* __restrict__ B,
                                                 long long strideA, long long strideB,
                                                 void* p0, void* p1, void* p2,
                                                 const void* p3) {
    constexpr int K = NT * 32;
    __shared__ __align__(16) unsigned short As[2][128 * 32];
    __shared__ __align__(16) unsigned short Bs[2][256 * 32];
    int t = threadIdx.x;
    int w = t >> 6, lane = t & 63;
    int wc = w, c15 = lane & 15, qq = lane >> 4;
    int bx = blockIdx.x, by = blockIdx.y, bz = blockIdx.z;
    if constexpr (SWZ) {
        int gx = gridDim.x;
        int nb = gx * gridDim.y;
        int bid = by * gx + bx;
        int s = (bid & 7) * (nb >> 3) + (bid >> 3);
        bx = s % gx;
        by = s / gx;
    }
    const unsigned short* Ab = A + bz * strideA + (long long)by * 128 * K;
    const unsigned short* Bb = B + bz * strideB + (long long)bx * 256 * K;

    f32x4 acc[8][4];
#pragma unroll
    for (int m = 0; m < 8; ++m)
#pragma unroll
        for (int n = 0; n < 4; ++n) acc[m][n] = (f32x4){0.f, 0.f, 0.f, 0.f};

    bool swapped = true;
    if constexpr (EPI == 10) {
        swapped = !(bx >= 6 && bx < 12);
        if (swapped)
            ring_kloop<true, NT>(Ab, Bb, &As[0][0], &As[1][0], &Bs[0][0], &Bs[1][0],
                                 acc, t, wc, c15, qq);
        else
            ring_kloop<false, NT>(Ab, Bb, &As[0][0], &As[1][0], &Bs[0][0], &Bs[1][0],
                                  acc, t, wc, c15, qq);
    } else {
        ring_kloop<true, NT>(Ab, Bb, &As[0][0], &As[1][0], &Bs[0][0], &Bs[1][0],
                             acc, t, wc, c15, qq);
    }

    if constexpr (EPI == 10) {
        if (swapped) {  // u (bx<6) or bS (bx==12): row-major, cols contiguous
            int rowb = by * 128 + c15;
            int colb = bx * 256 + wc * 64 + (qq << 2);
#pragma unroll
            for (int m = 0; m < 8; ++m) {
#pragma unroll
                for (int n = 0; n < 4; ++n) {
                    int R = rowb + m * 16;
                    int C = colb + n * 16;
                    f32x4 a = acc[m][n];
                    if (C < 1536) {
                        f32x4 bb = *(const f32x4*)((const float*)p3 + C);
                        u16x4 o;
#pragma unroll
                        for (int i = 0; i < 4; ++i) o[i] = f2b(silu(a[i] + bb[i]));
                        *(u16x4*)((unsigned short*)p0 + (long long)R * 1536 + C) = o;
                    } else if (C < 3200) {  // bS
                        f32x4 bb = *(const f32x4*)((const float*)p3 + C);
                        u16x4 o;
#pragma unroll
                        for (int i = 0; i < 4; ++i) o[i] = f2b(silu(a[i] + bb[i]));
                        *(u16x4*)((unsigned short*)p2 + (long long)R * 128 + (C - 3072)) = o;
                    }
                }
            }
        } else {  // vT: thread holds 4 consecutive rows at one col
            int rowb = by * 128 + (qq << 2);
            int colb = bx * 256 + wc * 64 + c15;
#pragma unroll
            for (int m = 0; m < 8; ++m) {
#pragma unroll
                for (int n = 0; n < 4; ++n) {
                    int R = rowb + m * 16;
                    int C = colb + n * 16;   // 1536..3071
                    float bias = ((const float*)p3)[C];
                    f32x4 a = acc[m][n];
                    u16x4 o;
#pragma unroll
                    for (int i = 0; i < 4; ++i) o[i] = f2b(silu(a[i] + bias));
                    int bb2 = R >> 9, mm = R & 511;
                    *(u16x4*)((unsigned short*)p1 +
                              ((long long)bb2 * 1536 + (C - 1536)) * 512 + mm) = o;
                }
            }
        }
    } else if constexpr (EPI == 2) {
        int rowb = by * 128 + c15;
        int colb = bx * 256 + wc * 64 + (qq << 2);
#pragma unroll
        for (int m = 0; m < 8; ++m) {
#pragma unroll
            for (int n = 0; n < 4; ++n) {
                int R = rowb + m * 16;
                int C = colb + n * 16;
                f32x4 a = acc[m][n];
                long long idx = ((long long)(bz * 512 + R)) * 1536 + C;
                u16x4 uu = *(const u16x4*)((const unsigned short*)p1 + idx);
                u16x4 o;
#pragma unroll
                for (int i = 0; i < 4; ++i) o[i] = f2b(a[i] * b2f(uu[i]));
                *(u16x4*)((unsigned short*)p0 + idx) = o;
            }
        }
    } else {  // EPI == 3
        int rowb = by * 128 + c15;
        int colb = bx * 256 + wc * 64 + (qq << 2);
#pragma unroll
        for (int m = 0; m < 8; ++m) {
#pragma unroll
            for (int n = 0; n < 4; ++n) {
                int R = rowb + m * 16;
                int C = colb + n * 16;
                f32x4 a = acc[m][n];
                long long idx = (long long)R * 768 + C;
                f32x4 xv = *(const f32x4*)((const float*)p2 + idx);
                f32x4 ob = *(const f32x4*)((const float*)p1 + C);
                f32x4 o;
#pragma unroll
                for (int i = 0; i < 4; ++i) o[i] = a[i] + ob[i] + xv[i];
                *(f32x4*)((float*)p0 + idx) = o;
            }
        }
    }
}

extern "C" void kernel_launch(void* const* d_in, const int* in_sizes, int n_in,
                              void* d_out, int out_size, void* d_ws, size_t ws_size,
                              hipStream_t stream) {
    const float* x     = (const float*)d_in[0];
    const float* ln_g  = (const float*)d_in[1];
    const float* ln_b  = (const float*)d_in[2];
    const float* uv_W  = (const float*)d_in[3];
    const float* uv_b  = (const float*)d_in[4];
    const float* g_qk  = (const float*)d_in[5];
    const float* b_qk  = (const float*)d_in[6];
    const float* w_rel = (const float*)d_in[7];
    const float* o_W   = (const float*)d_in[8];
    const float* o_b   = (const float*)d_in[9];
    float* out = (float*)d_out;

    char* ws = (char*)d_ws;
    size_t off = 0;
    auto alloc = [&](size_t bytes) {
        void* p = ws + off;
        off += (bytes + 255) & ~(size_t)255;
        return p;
    };
    unsigned short* uvWT = (unsigned short*)alloc(3200ll * 768 * 2);
    unsigned short* oWT  = (unsigned short*)alloc(768ll * 1536 * 2);
    unsigned short* xn   = (unsigned short*)alloc(16384ll * 768 * 2);
    unsigned short* u    = (unsigned short*)alloc(16384ll * 1536 * 2);
    unsigned short* vT   = (unsigned short*)alloc(32ll * 1536 * 512 * 2);
    unsigned short* bS   = (unsigned short*)alloc(16384ll * 128 * 2);
    unsigned short* q    = (unsigned short*)alloc(32ll * 512 * 128 * 2);
    unsigned short* k    = (unsigned short*)alloc(32ll * 512 * 128 * 2);
    unsigned short* P     = xn;  // alias: xn dead after UV kernel
    unsigned short* gated = u;   // alias: same-thread read-then-write

    k_convT<<<dim3(100, 24), dim3(32, 8), 0, stream>>>(uv_W, uvWT, 768, 3200);
    k_convT<<<dim3(24, 48), dim3(32, 8), 0, stream>>>(o_W, oWT, 1536, 768);
    k_ln<<<16384, 256, 0, stream>>>(x, ln_g, ln_b, xn);
    // UV merged: u | vT | bS   (N=3328 incl. 128 masked cols; K=768 -> NT=24)
    k_ring<10, true, 24><<<dim3(13, 128), 256, 0, stream>>>(
        xn, uvWT, 0, 0, (void*)u, (void*)vT, (void*)bS, (const void*)uv_b);
    k_rope<<<16384, 128, 0, stream>>>(bS, g_qk, b_qk, q, k);
    // QK^T -> P
    k_qk<<<dim3(4, 4, 32), 256, 0, stream>>>(q, k, w_rel, P);
    // PV gated by u   (K=512 -> NT=16)
    k_ring<2, false, 16><<<dim3(6, 4, 32), 256, 0, stream>>>(
        P, vT, 512ll * 512, 1536ll * 512, (void*)gated, (void*)u, nullptr, nullptr);
    // out = gated @ oWT^T + o_b + x   (K=1536 -> NT=48)
    k_ring<3, true, 48><<<dim3(3, 128), 256, 0, stream>>>(
        gated, oWT, 0, 0, (void*)out, (void*)o_b, (void*)x, nullptr);
}

// Round 6
// 296.747 us; speedup vs baseline: 1.1006x; 1.0127x over previous
//
#include <hip/hip_runtime.h>
#include <hip/hip_bf16.h>
#include <math.h>

typedef __bf16 bf16x8 __attribute__((ext_vector_type(8)));
typedef float f32x4 __attribute__((ext_vector_type(4)));
typedef unsigned short u16x4 __attribute__((ext_vector_type(4)));

#define AS1P const __attribute__((address_space(1))) void*
#define AS3P __attribute__((address_space(3))) void*

__device__ __forceinline__ float b2f(unsigned short h) {
    unsigned int u = ((unsigned int)h) << 16;
    return __builtin_bit_cast(float, u);
}
__device__ __forceinline__ unsigned short f2b(float f) {
    unsigned int u = __builtin_bit_cast(unsigned int, f);
    u += 0x7FFFu + ((u >> 16) & 1u);
    return (unsigned short)(u >> 16);
}
__device__ __forceinline__ float silu(float c) {
    return c * __builtin_amdgcn_rcpf(1.0f + __expf(-c));
}

// ---------------- tiled transpose + bf16 convert
__global__ __launch_bounds__(256) void k_convT(const float* __restrict__ src,
                                               unsigned short* __restrict__ dst,
                                               int R, int C) {
    __shared__ float tile[32][33];
    int tx = threadIdx.x, ty = threadIdx.y;
    int r0 = blockIdx.y << 5, c0 = blockIdx.x << 5;
#pragma unroll
    for (int i = 0; i < 4; ++i)
        tile[ty + 8 * i][tx] = src[(long long)(r0 + ty + 8 * i) * C + c0 + tx];
    __syncthreads();
#pragma unroll
    for (int i = 0; i < 4; ++i)
        dst[(long long)(c0 + ty + 8 * i) * R + r0 + tx] = f2b(tile[tx][ty + 8 * i]);
}

// ---------------- LayerNorm
__global__ __launch_bounds__(256) void k_ln(const float* __restrict__ x,
                                            const float* __restrict__ g,
                                            const float* __restrict__ b,
                                            unsigned short* __restrict__ xn) {
    int row = blockIdx.x;
    int t = threadIdx.x;
    const float* xr = x + (long long)row * 768;
    float v0 = xr[t], v1 = xr[t + 256], v2 = xr[t + 512];
    float s = v0 + v1 + v2;
    float q = v0 * v0 + v1 * v1 + v2 * v2;
#pragma unroll
    for (int off = 32; off > 0; off >>= 1) {
        s += __shfl_xor(s, off);
        q += __shfl_xor(q, off);
    }
    __shared__ float ss[4], sq[4];
    int w = t >> 6;
    if ((t & 63) == 0) { ss[w] = s; sq[w] = q; }
    __syncthreads();
    float S_ = ss[0] + ss[1] + ss[2] + ss[3];
    float Q_ = sq[0] + sq[1] + sq[2] + sq[3];
    float mu = S_ * (1.0f / 768.0f);
    float var = Q_ * (1.0f / 768.0f) - mu * mu;
    float rs = rsqrtf(var + 1e-5f);
    unsigned short* xo = xn + (long long)row * 768;
    xo[t]       = f2b((v0 - mu) * rs * g[t]       + b[t]);
    xo[t + 256] = f2b((v1 - mu) * rs * g[t + 256] + b[t + 256]);
    xo[t + 512] = f2b((v2 - mu) * rs * g[t + 512] + b[t + 512]);
}

// ---------------- RoPE + per-head affine
__global__ __launch_bounds__(128) void k_rope(const unsigned short* __restrict__ bS,
                                              const float* __restrict__ gqk,
                                              const float* __restrict__ bqk,
                                              unsigned short* __restrict__ q,
                                              unsigned short* __restrict__ k) {
    int row = blockIdx.x;
    int l = row & 511;
    int s = threadIdx.x;
    int j = s & 63;
    int partner = s ^ 64;
    float b0 = b2f(bS[(long long)row * 128 + s]);
    float bp = b2f(bS[(long long)row * 128 + partner]);
    float invf = __expf((float)j * -0.14391156831f);
    float th = (float)l * invf;
    float sn, cs;
    __sincosf(th, &sn, &cs);
    float sign = (s < 64) ? -1.0f : 1.0f;
    float preq  = b0 * gqk[s]           + bqk[s];
    float preqp = bp * gqk[partner]     + bqk[partner];
    q[(long long)row * 128 + s] = f2b(preq * cs + sign * preqp * sn);
    float prek  = b0 * gqk[128 + s]       + bqk[128 + s];
    float prekp = bp * gqk[128 + partner] + bqk[128 + partner];
    k[(long long)row * 128 + s] = f2b(prek * cs + sign * prekp * sn);
}

// ================= 128^2 2-phase kernel (QK only: P = relu^2(qk/L + bias))
__global__ __launch_bounds__(256) void k_qk(const unsigned short* __restrict__ A,
                                            const unsigned short* __restrict__ B,
                                            const float* __restrict__ wrel,
                                            unsigned short* __restrict__ P) {
    __shared__ __align__(16) unsigned short As[128 * 64];
    __shared__ __align__(16) unsigned short Bs[128 * 64];
    int t = threadIdx.x;
    int w = t >> 6, lane = t & 63;
    int wr = w >> 1, wc = w & 1;
    int bx = blockIdx.x, by = blockIdx.y, bz = blockIdx.z;
    const unsigned short* Ab = A + (long long)bz * 512 * 128 + (long long)by * 128 * 128;
    const unsigned short* Bb = B + (long long)bz * 512 * 128 + (long long)bx * 128 * 128;

    f32x4 acc[4][4];
#pragma unroll
    for (int m = 0; m < 4; ++m)
#pragma unroll
        for (int n = 0; n < 4; ++n) acc[m][n] = (f32x4){0.f, 0.f, 0.f, 0.f};

    int rowA = (w << 3) + (lane >> 3);
    int colA = (lane & 7) << 3;

    for (int k0 = 0; k0 < 128; k0 += 64) {
#pragma unroll
        for (int i = 0; i < 4; ++i) {
            int r = (i << 5) + rowA;
            __builtin_amdgcn_global_load_lds(
                (AS1P)(Ab + (long long)r * 128 + k0 + colA),
                (AS3P)(&As[(i << 11) + (w << 9)]), 16, 0, 0);
            __builtin_amdgcn_global_load_lds(
                (AS1P)(Bb + (long long)r * 128 + k0 + colA),
                (AS3P)(&Bs[(i << 11) + (w << 9)]), 16, 0, 0);
        }
        __syncthreads();
#pragma unroll
        for (int ks = 0; ks < 2; ++ks) {
            bf16x8 af[4], bfr[4];
#pragma unroll
            for (int m = 0; m < 4; ++m)
                af[m] = *(const bf16x8*)&As[((wr << 6) + (m << 4) + (lane & 15)) * 64 +
                                            (ks << 5) + ((lane >> 4) << 3)];
#pragma unroll
            for (int n = 0; n < 4; ++n)
                bfr[n] = *(const bf16x8*)&Bs[((wc << 6) + (n << 4) + (lane & 15)) * 64 +
                                             (ks << 5) + ((lane >> 4) << 3)];
#pragma unroll
            for (int m = 0; m < 4; ++m)
#pragma unroll
                for (int n = 0; n < 4; ++n)
                    acc[m][n] = __builtin_amdgcn_mfma_f32_16x16x32_bf16(bfr[n], af[m],
                                                                        acc[m][n], 0, 0, 0);
        }
        __syncthreads();
    }

    int c15 = lane & 15, qq = lane >> 4;
    int rowb = (by << 7) + (wr << 6) + c15;
    int colb = (bx << 7) + (wc << 6) + (qq << 2);
#pragma unroll
    for (int m = 0; m < 4; ++m) {
#pragma unroll
        for (int n = 0; n < 4; ++n) {
            int grow = rowb + (m << 4);
            int gcol = colb + (n << 4);
            f32x4 a = acc[m][n];
            int base = gcol - grow + 511;
            u16x4 o;
#pragma unroll
            for (int i = 0; i < 4; ++i) {
                float val = a[i] * (1.0f / 512.0f) + wrel[base + i];
                val = fmaxf(val, 0.0f);
                o[i] = f2b(val * val);
            }
            *(u16x4*)(P + ((long long)(bz * 512 + grow)) * 512 + gcol) = o;
        }
    }
}

// ================= 128x256 3-slot ring kernel: BK=32, counted vmcnt(6),
// ONE barrier/iter, stage-at-top (2-iter hiding window), granule swizzle.
__device__ __forceinline__ bf16x8 ldsread(const unsigned short* p) {
    bf16x8 r;
    unsigned int off =
        (unsigned int)(unsigned long long)(__attribute__((address_space(3))) const void*)p;
    asm volatile("ds_read_b128 %0, %1" : "=v"(r) : "v"(off));
    return r;
}
__device__ __forceinline__ bf16x8 frag32(const unsigned short* tile, int r, int qq) {
    return ldsread(tile + r * 32 + ((qq ^ ((r >> 1) & 3)) << 3));
}
template <int ROWS, int K>
__device__ __forceinline__ void stage_t(const unsigned short* __restrict__ g,
                                        unsigned short* lds, int t) {
#pragma unroll
    for (int i = 0; i < ROWS / 64; ++i) {
        int slot = t + (i << 8);
        int row = slot >> 2;
        int gs = (slot & 3) ^ ((row >> 1) & 3);
        __builtin_amdgcn_global_load_lds(
            (AS1P)(g + (long long)row * K + (gs << 3)),
            (AS3P)(lds + slot * 8), 16, 0, 0);
    }
}

template <bool SWAP, int NT>
__device__ __forceinline__ void ring_kloop(const unsigned short* __restrict__ Ab,
                                           const unsigned short* __restrict__ Bb,
                                           unsigned short* As, unsigned short* Bs,
                                           f32x4 (&acc)[8][4], int t, int wc, int c15, int qq) {
    constexpr int K = NT * 32;
    constexpr int ASLOT = 128 * 32, BSLOT = 256 * 32;
    // prologue: stage tiles 0,1 into slots 0,1
    stage_t<128, K>(Ab, As, t);
    stage_t<256, K>(Bb, Bs, t);
    stage_t<128, K>(Ab + 32, As + ASLOT, t);
    stage_t<256, K>(Bb + 32, Bs + BSLOT, t);
    int slot = 0;
    for (int kt = 0; kt < NT; ++kt) {
        if (kt < NT - 1)
            asm volatile("s_waitcnt vmcnt(6)" ::: "memory");
        else
            asm volatile("s_waitcnt vmcnt(0)" ::: "memory");
        __builtin_amdgcn_s_barrier();  // tile kt resident; slot (kt+2)%3 free
        __builtin_amdgcn_sched_barrier(0);
        if (kt + 2 < NT) {
            int ns = slot + 2;
            if (ns >= 3) ns -= 3;
            stage_t<128, K>(Ab + (long long)(kt + 2) * 32, As + ns * ASLOT, t);
            stage_t<256, K>(Bb + (long long)(kt + 2) * 32, Bs + ns * BSLOT, t);
        }
        const unsigned short* At = As + slot * ASLOT;
        const unsigned short* Bt = Bs + slot * BSLOT;
        bf16x8 af[8], bfr[4];
#pragma unroll
        for (int n = 0; n < 4; ++n) bfr[n] = frag32(Bt, wc * 64 + n * 16 + c15, qq);
#pragma unroll
        for (int m = 0; m < 8; ++m) af[m] = frag32(At, m * 16 + c15, qq);
        asm volatile("s_waitcnt lgkmcnt(0)" ::: "memory");
        __builtin_amdgcn_sched_barrier(0);
        __builtin_amdgcn_s_setprio(1);
#pragma unroll
        for (int m = 0; m < 8; ++m)
#pragma unroll
            for (int n = 0; n < 4; ++n) {
                if constexpr (SWAP)
                    acc[m][n] = __builtin_amdgcn_mfma_f32_16x16x32_bf16(bfr[n], af[m],
                                                                        acc[m][n], 0, 0, 0);
                else
                    acc[m][n] = __builtin_amdgcn_mfma_f32_16x16x32_bf16(af[m], bfr[n],
                                                                        acc[m][n], 0, 0, 0);
            }
        __builtin_amdgcn_s_setprio(0);
        slot = (slot + 1 == 3) ? 0 : slot + 1;
    }
}

// EPI: 10 = UV merged (u | vT | bS by bx)   2 = gated(PV*u)   3 = out f32(+o_b+x)
template <int EPI, bool SWZ, int NT>
__global__ __launch_bounds__(256, 2) void k_ring(const unsigned short* __restrict__ A,
                                                 const unsigned short* __restrict__ B,
                                                 long long strideA, long long strideB,
                                                 void* p0, void* p1, void* p2,
                                                 const void* p3) {
    constexpr int K = NT * 32;
    __shared__ __align__(16) unsigned short As[3][128 * 32];
    __shared__ __align__(16) unsigned short Bs[3][256 * 32];
    int t = threadIdx.x;
    int w = t >> 6, lane = t & 63;
    int wc = w, c15 = lane & 15, qq = lane >> 4;
    int bx = blockIdx.x, by = blockIdx.y, bz = blockIdx.z;
    if constexpr (SWZ) {
        int gx = gridDim.x;
        int nb = gx * gridDim.y;
        int bid = by * gx + bx;
        int s = (bid & 7) * (nb >> 3) + (bid >> 3);
        bx = s % gx;
        by = s / gx;
    }
    const unsigned short* Ab = A + bz * strideA + (long long)by * 128 * K;
    const unsigned short* Bb = B + bz * strideB + (long long)bx * 256 * K;

    f32x4 acc[8][4];
#pragma unroll
    for (int m = 0; m < 8; ++m)
#pragma unroll
        for (int n = 0; n < 4; ++n) acc[m][n] = (f32x4){0.f, 0.f, 0.f, 0.f};

    bool swapped = true;
    if constexpr (EPI == 10) {
        swapped = !(bx >= 6 && bx < 12);
        if (swapped)
            ring_kloop<true, NT>(Ab, Bb, &As[0][0], &Bs[0][0], acc, t, wc, c15, qq);
        else
            ring_kloop<false, NT>(Ab, Bb, &As[0][0], &Bs[0][0], acc, t, wc, c15, qq);
    } else {
        ring_kloop<true, NT>(Ab, Bb, &As[0][0], &Bs[0][0], acc, t, wc, c15, qq);
    }

    if constexpr (EPI == 10) {
        if (swapped) {  // u (bx<6) or bS (bx==12): row-major, cols contiguous
            int rowb = by * 128 + c15;
            int colb = bx * 256 + wc * 64 + (qq << 2);
#pragma unroll
            for (int m = 0; m < 8; ++m) {
#pragma unroll
                for (int n = 0; n < 4; ++n) {
                    int R = rowb + m * 16;
                    int C = colb + n * 16;
                    f32x4 a = acc[m][n];
                    if (C < 1536) {
                        f32x4 bb = *(const f32x4*)((const float*)p3 + C);
                        u16x4 o;
#pragma unroll
                        for (int i = 0; i < 4; ++i) o[i] = f2b(silu(a[i] + bb[i]));
                        *(u16x4*)((unsigned short*)p0 + (long long)R * 1536 + C) = o;
                    } else if (C < 3200) {  // bS
                        f32x4 bb = *(const f32x4*)((const float*)p3 + C);
                        u16x4 o;
#pragma unroll
                        for (int i = 0; i < 4; ++i) o[i] = f2b(silu(a[i] + bb[i]));
                        *(u16x4*)((unsigned short*)p2 + (long long)R * 128 + (C - 3072)) = o;
                    }
                }
            }
        } else {  // vT: thread holds 4 consecutive rows at one col
            int rowb = by * 128 + (qq << 2);
            int colb = bx * 256 + wc * 64 + c15;
#pragma unroll
            for (int m = 0; m < 8; ++m) {
#pragma unroll
                for (int n = 0; n < 4; ++n) {
                    int R = rowb + m * 16;
                    int C = colb + n * 16;   // 1536..3071
                    float bias = ((const float*)p3)[C];
                    f32x4 a = acc[m][n];
                    u16x4 o;
#pragma unroll
                    for (int i = 0; i < 4; ++i) o[i] = f2b(silu(a[i] + bias));
                    int bb2 = R >> 9, mm = R & 511;
                    *(u16x4*)((unsigned short*)p1 +
                              ((long long)bb2 * 1536 + (C - 1536)) * 512 + mm) = o;
                }
            }
        }
    } else if constexpr (EPI == 2) {
        int rowb = by * 128 + c15;
        int colb = bx * 256 + wc * 64 + (qq << 2);
#pragma unroll
        for (int m = 0; m < 8; ++m) {
#pragma unroll
            for (int n = 0; n < 4; ++n) {
                int R = rowb + m * 16;
                int C = colb + n * 16;
                f32x4 a = acc[m][n];
                long long idx = ((long long)(bz * 512 + R)) * 1536 + C;
                u16x4 uu = *(const u16x4*)((const unsigned short*)p1 + idx);
                u16x4 o;
#pragma unroll
                for (int i = 0; i < 4; ++i) o[i] = f2b(a[i] * b2f(uu[i]));
                *(u16x4*)((unsigned short*)p0 + idx) = o;
            }
        }
    } else {  // EPI == 3
        int rowb = by * 128 + c15;
        int colb = bx * 256 + wc * 64 + (qq << 2);
#pragma unroll
        for (int m = 0; m < 8; ++m) {
#pragma unroll
            for (int n = 0; n < 4; ++n) {
                int R = rowb + m * 16;
                int C = colb + n * 16;
                f32x4 a = acc[m][n];
                long long idx = (long long)R * 768 + C;
                f32x4 xv = *(const f32x4*)((const float*)p2 + idx);
                f32x4 ob = *(const f32x4*)((const float*)p1 + C);
                f32x4 o;
#pragma unroll
                for (int i = 0; i < 4; ++i) o[i] = a[i] + ob[i] + xv[i];
                *(f32x4*)((float*)p0 + idx) = o;
            }
        }
    }
}

extern "C" void kernel_launch(void* const* d_in, const int* in_sizes, int n_in,
                              void* d_out, int out_size, void* d_ws, size_t ws_size,
                              hipStream_t stream) {
    const float* x     = (const float*)d_in[0];
    const float* ln_g  = (const float*)d_in[1];
    const float* ln_b  = (const float*)d_in[2];
    const float* uv_W  = (const float*)d_in[3];
    const float* uv_b  = (const float*)d_in[4];
    const float* g_qk  = (const float*)d_in[5];
    const float* b_qk  = (const float*)d_in[6];
    const float* w_rel = (const float*)d_in[7];
    const float* o_W   = (const float*)d_in[8];
    const float* o_b   = (const float*)d_in[9];
    float* out = (float*)d_out;

    char* ws = (char*)d_ws;
    size_t off = 0;
    auto alloc = [&](size_t bytes) {
        void* p = ws + off;
        off += (bytes + 255) & ~(size_t)255;
        return p;
    };
    unsigned short* uvWT = (unsigned short*)alloc(3200ll * 768 * 2);
    unsigned short* oWT  = (unsigned short*)alloc(768ll * 1536 * 2);
    unsigned short* xn   = (unsigned short*)alloc(16384ll * 768 * 2);
    unsigned short* u    = (unsigned short*)alloc(16384ll * 1536 * 2);
    unsigned short* vT   = (unsigned short*)alloc(32ll * 1536 * 512 * 2);
    unsigned short* bS   = (unsigned short*)alloc(16384ll * 128 * 2);
    unsigned short* q    = (unsigned short*)alloc(32ll * 512 * 128 * 2);
    unsigned short* k    = (unsigned short*)alloc(32ll * 512 * 128 * 2);
    unsigned short* P     = xn;  // alias: xn dead after UV kernel
    unsigned short* gated = u;   // alias: same-thread read-then-write

    k_convT<<<dim3(100, 24), dim3(32, 8), 0, stream>>>(uv_W, uvWT, 768, 3200);
    k_convT<<<dim3(24, 48), dim3(32, 8), 0, stream>>>(o_W, oWT, 1536, 768);
    k_ln<<<16384, 256, 0, stream>>>(x, ln_g, ln_b, xn);
    // UV merged: u | vT | bS   (N=3328 incl. 128 masked cols; K=768 -> NT=24)
    k_ring<10, true, 24><<<dim3(13, 128), 256, 0, stream>>>(
        xn, uvWT, 0, 0, (void*)u, (void*)vT, (void*)bS, (const void*)uv_b);
    k_rope<<<16384, 128, 0, stream>>>(bS, g_qk, b_qk, q, k);
    // QK^T -> P
    k_qk<<<dim3(4, 4, 32), 256, 0, stream>>>(q, k, w_rel, P);
    // PV gated by u   (K=512 -> NT=16)
    k_ring<2, false, 16><<<dim3(6, 4, 32), 256, 0, stream>>>(
        P, vT, 512ll * 512, 1536ll * 512, (void*)gated, (void*)u, nullptr, nullptr);
    // out = gated @ oWT^T + o_b + x   (K=1536 -> NT=48)
    k_ring<3, true, 48><<<dim3(3, 128), 256, 0, stream>>>(
        gated, oWT, 0, 0, (void*)out, (void*)o_b, (void*)x, nullptr);
}

// Round 7
// 291.791 us; speedup vs baseline: 1.1193x; 1.0170x over previous
//
#include <hip/hip_runtime.h>
#include <hip/hip_bf16.h>
#include <math.h>

typedef __bf16 bf16x8 __attribute__((ext_vector_type(8)));
typedef float f32x4 __attribute__((ext_vector_type(4)));
typedef unsigned short u16x4 __attribute__((ext_vector_type(4)));

#define AS1P const __attribute__((address_space(1))) void*
#define AS3P __attribute__((address_space(3))) void*

__device__ __forceinline__ float b2f(unsigned short h) {
    unsigned int u = ((unsigned int)h) << 16;
    return __builtin_bit_cast(float, u);
}
__device__ __forceinline__ unsigned short f2b(float f) {
    unsigned int u = __builtin_bit_cast(unsigned int, f);
    u += 0x7FFFu + ((u >> 16) & 1u);
    return (unsigned short)(u >> 16);
}
__device__ __forceinline__ float silu(float c) {
    return c * __builtin_amdgcn_rcpf(1.0f + __expf(-c));
}

// ---------------- tiled transpose + bf16 convert
__global__ __launch_bounds__(256) void k_convT(const float* __restrict__ src,
                                               unsigned short* __restrict__ dst,
                                               int R, int C) {
    __shared__ float tile[32][33];
    int tx = threadIdx.x, ty = threadIdx.y;
    int r0 = blockIdx.y << 5, c0 = blockIdx.x << 5;
#pragma unroll
    for (int i = 0; i < 4; ++i)
        tile[ty + 8 * i][tx] = src[(long long)(r0 + ty + 8 * i) * C + c0 + tx];
    __syncthreads();
#pragma unroll
    for (int i = 0; i < 4; ++i)
        dst[(long long)(c0 + ty + 8 * i) * R + r0 + tx] = f2b(tile[tx][ty + 8 * i]);
}

// ---------------- LayerNorm
__global__ __launch_bounds__(256) void k_ln(const float* __restrict__ x,
                                            const float* __restrict__ g,
                                            const float* __restrict__ b,
                                            unsigned short* __restrict__ xn) {
    int row = blockIdx.x;
    int t = threadIdx.x;
    const float* xr = x + (long long)row * 768;
    float v0 = xr[t], v1 = xr[t + 256], v2 = xr[t + 512];
    float s = v0 + v1 + v2;
    float q = v0 * v0 + v1 * v1 + v2 * v2;
#pragma unroll
    for (int off = 32; off > 0; off >>= 1) {
        s += __shfl_xor(s, off);
        q += __shfl_xor(q, off);
    }
    __shared__ float ss[4], sq[4];
    int w = t >> 6;
    if ((t & 63) == 0) { ss[w] = s; sq[w] = q; }
    __syncthreads();
    float S_ = ss[0] + ss[1] + ss[2] + ss[3];
    float Q_ = sq[0] + sq[1] + sq[2] + sq[3];
    float mu = S_ * (1.0f / 768.0f);
    float var = Q_ * (1.0f / 768.0f) - mu * mu;
    float rs = rsqrtf(var + 1e-5f);
    unsigned short* xo = xn + (long long)row * 768;
    xo[t]       = f2b((v0 - mu) * rs * g[t]       + b[t]);
    xo[t + 256] = f2b((v1 - mu) * rs * g[t + 256] + b[t + 256]);
    xo[t + 512] = f2b((v2 - mu) * rs * g[t + 512] + b[t + 512]);
}

// ---------------- RoPE + per-head affine
__global__ __launch_bounds__(128) void k_rope(const unsigned short* __restrict__ bS,
                                              const float* __restrict__ gqk,
                                              const float* __restrict__ bqk,
                                              unsigned short* __restrict__ q,
                                              unsigned short* __restrict__ k) {
    int row = blockIdx.x;
    int l = row & 511;
    int s = threadIdx.x;
    int j = s & 63;
    int partner = s ^ 64;
    float b0 = b2f(bS[(long long)row * 128 + s]);
    float bp = b2f(bS[(long long)row * 128 + partner]);
    float invf = __expf((float)j * -0.14391156831f);
    float th = (float)l * invf;
    float sn, cs;
    __sincosf(th, &sn, &cs);
    float sign = (s < 64) ? -1.0f : 1.0f;
    float preq  = b0 * gqk[s]           + bqk[s];
    float preqp = bp * gqk[partner]     + bqk[partner];
    q[(long long)row * 128 + s] = f2b(preq * cs + sign * preqp * sn);
    float prek  = b0 * gqk[128 + s]       + bqk[128 + s];
    float prekp = bp * gqk[128 + partner] + bqk[128 + partner];
    k[(long long)row * 128 + s] = f2b(prek * cs + sign * prekp * sn);
}

// ================= 128^2 2-phase kernel (QK only: P = relu^2(qk/L + bias))
__global__ __launch_bounds__(256) void k_qk(const unsigned short* __restrict__ A,
                                            const unsigned short* __restrict__ B,
                                            const float* __restrict__ wrel,
                                            unsigned short* __restrict__ P) {
    __shared__ __align__(16) unsigned short As[128 * 64];
    __shared__ __align__(16) unsigned short Bs[128 * 64];
    int t = threadIdx.x;
    int w = t >> 6, lane = t & 63;
    int wr = w >> 1, wc = w & 1;
    int bx = blockIdx.x, by = blockIdx.y, bz = blockIdx.z;
    const unsigned short* Ab = A + (long long)bz * 512 * 128 + (long long)by * 128 * 128;
    const unsigned short* Bb = B + (long long)bz * 512 * 128 + (long long)bx * 128 * 128;

    f32x4 acc[4][4];
#pragma unroll
    for (int m = 0; m < 4; ++m)
#pragma unroll
        for (int n = 0; n < 4; ++n) acc[m][n] = (f32x4){0.f, 0.f, 0.f, 0.f};

    int rowA = (w << 3) + (lane >> 3);
    int colA = (lane & 7) << 3;

    for (int k0 = 0; k0 < 128; k0 += 64) {
#pragma unroll
        for (int i = 0; i < 4; ++i) {
            int r = (i << 5) + rowA;
            __builtin_amdgcn_global_load_lds(
                (AS1P)(Ab + (long long)r * 128 + k0 + colA),
                (AS3P)(&As[(i << 11) + (w << 9)]), 16, 0, 0);
            __builtin_amdgcn_global_load_lds(
                (AS1P)(Bb + (long long)r * 128 + k0 + colA),
                (AS3P)(&Bs[(i << 11) + (w << 9)]), 16, 0, 0);
        }
        __syncthreads();
#pragma unroll
        for (int ks = 0; ks < 2; ++ks) {
            bf16x8 af[4], bfr[4];
#pragma unroll
            for (int m = 0; m < 4; ++m)
                af[m] = *(const bf16x8*)&As[((wr << 6) + (m << 4) + (lane & 15)) * 64 +
                                            (ks << 5) + ((lane >> 4) << 3)];
#pragma unroll
            for (int n = 0; n < 4; ++n)
                bfr[n] = *(const bf16x8*)&Bs[((wc << 6) + (n << 4) + (lane & 15)) * 64 +
                                             (ks << 5) + ((lane >> 4) << 3)];
#pragma unroll
            for (int m = 0; m < 4; ++m)
#pragma unroll
                for (int n = 0; n < 4; ++n)
                    acc[m][n] = __builtin_amdgcn_mfma_f32_16x16x32_bf16(bfr[n], af[m],
                                                                        acc[m][n], 0, 0, 0);
        }
        __syncthreads();
    }

    int c15 = lane & 15, qq = lane >> 4;
    int rowb = (by << 7) + (wr << 6) + c15;
    int colb = (bx << 7) + (wc << 6) + (qq << 2);
#pragma unroll
    for (int m = 0; m < 4; ++m) {
#pragma unroll
        for (int n = 0; n < 4; ++n) {
            int grow = rowb + (m << 4);
            int gcol = colb + (n << 4);
            f32x4 a = acc[m][n];
            int base = gcol - grow + 511;
            u16x4 o;
#pragma unroll
            for (int i = 0; i < 4; ++i) {
                float val = a[i] * (1.0f / 512.0f) + wrel[base + i];
                val = fmaxf(val, 0.0f);
                o[i] = f2b(val * val);
            }
            *(u16x4*)(P + ((long long)(bz * 512 + grow)) * 512 + gcol) = o;
        }
    }
}

// ================= 256x256 8-phase kernel (m201-style): BK=64, 512 thr, 8 waves 2x4.
// LDS [buf][khalf][256][32] (each K-half contiguous 16KB = stageable half-tile).
// Phase p of K-tile t: ks=p>>1, mh=p&1; reads only K-half ks; 16 MFMA.
// Stage order: ph0->A-K1(t+1), ph1->B-K1(t+1), ph2->A-K0(t+2), ph3->B-K0(t+2).
// Waits: vmcnt(8) at ends of ph1/ph3 (tail: 8->4->0). Granule swizzle g^=(row>>1)&3.
__device__ __forceinline__ bf16x8 ldsread(const unsigned short* p) {
    bf16x8 r;
    unsigned int off =
        (unsigned int)(unsigned long long)(__attribute__((address_space(3))) const void*)p;
    asm volatile("ds_read_b128 %0, %1" : "=v"(r) : "v"(off));
    return r;
}
// stage one half-tile: 256 rows x 32 cols (16KB), 512 threads x 2 loads.
__device__ __forceinline__ void stage_half(const unsigned short* __restrict__ g, int ldk,
                                           unsigned short* lds, int t) {
#pragma unroll
    for (int i = 0; i < 2; ++i) {
        int slot = t + (i << 9);
        int row = slot >> 2;
        int gs = (slot & 3) ^ ((slot >> 3) & 3);
        __builtin_amdgcn_global_load_lds(
            (AS1P)(g + (long long)row * ldk + (gs << 3)),
            (AS3P)(lds + slot * 8), 16, 0, 0);
    }
}

template <bool SWAP, int NT>
__device__ __forceinline__ void kloop8(const unsigned short* __restrict__ Ab,
                                       const unsigned short* __restrict__ Bb,
                                       unsigned short* As, unsigned short* Bs,
                                       f32x4 (&acc)[8][4], int tid,
                                       int wr, int wc, int c15, int qq, int gq) {
    constexpr int K = NT * 64;
    // half-tile LDS bases: [(T&1)*2 + kh] * 8192
    // prologue: tile0 all 4 halves + tile1 K0 halves
    stage_half(Ab, K, As + 0, tid);
    stage_half(Bb, K, Bs + 0, tid);
    stage_half(Ab + 32, K, As + 8192, tid);
    stage_half(Bb + 32, K, Bs + 8192, tid);
    stage_half(Ab + 64, K, As + 16384, tid);
    stage_half(Bb + 64, K, Bs + 16384, tid);
    asm volatile("s_waitcnt vmcnt(8)" ::: "memory");
    __builtin_amdgcn_s_barrier();

    bf16x8 bfr[4], af[4];
    for (int t = 0; t < NT; ++t) {
        const int b = t & 1;
        const unsigned short* A0 = As + b * 16384;
        const unsigned short* B0 = Bs + b * 16384;
#pragma unroll
        for (int p = 0; p < 4; ++p) {
            const int ks = p >> 1, mh = p & 1;
            const unsigned short* At = A0 + ks * 8192;
            const unsigned short* Bt = B0 + ks * 8192;
            if (mh == 0) {
#pragma unroll
                for (int n = 0; n < 4; ++n)
                    bfr[n] = ldsread(Bt + (wc * 64 + n * 16 + c15) * 32 + gq * 8);
            }
#pragma unroll
            for (int j = 0; j < 4; ++j)
                af[j] = ldsread(At + (wr * 128 + (mh * 4 + j) * 16 + c15) * 32 + gq * 8);
            if (p == 0) {
                if (t + 1 < NT)
                    stage_half(Ab + (t + 1) * 64 + 32, K,
                               As + (((t + 1) & 1) * 2 + 1) * 8192, tid);
            } else if (p == 1) {
                if (t + 1 < NT)
                    stage_half(Bb + (t + 1) * 64 + 32, K,
                               Bs + (((t + 1) & 1) * 2 + 1) * 8192, tid);
            } else if (p == 2) {
                if (t + 2 < NT)
                    stage_half(Ab + (t + 2) * 64, K, As + (b * 2) * 8192, tid);
            } else {
                if (t + 2 < NT)
                    stage_half(Bb + (t + 2) * 64, K, Bs + (b * 2) * 8192, tid);
            }
            __builtin_amdgcn_s_barrier();
            asm volatile("s_waitcnt lgkmcnt(0)" ::: "memory");
            __builtin_amdgcn_sched_barrier(0);
            __builtin_amdgcn_s_setprio(1);
#pragma unroll
            for (int j = 0; j < 4; ++j)
#pragma unroll
                for (int n = 0; n < 4; ++n) {
                    if constexpr (SWAP)
                        acc[mh * 4 + j][n] = __builtin_amdgcn_mfma_f32_16x16x32_bf16(
                            bfr[n], af[j], acc[mh * 4 + j][n], 0, 0, 0);
                    else
                        acc[mh * 4 + j][n] = __builtin_amdgcn_mfma_f32_16x16x32_bf16(
                            af[j], bfr[n], acc[mh * 4 + j][n], 0, 0, 0);
                }
            __builtin_amdgcn_s_setprio(0);
            if (p == 1) {
                if (t < NT - 1)
                    asm volatile("s_waitcnt vmcnt(8)" ::: "memory");
                else
                    asm volatile("s_waitcnt vmcnt(0)" ::: "memory");
            } else if (p == 3) {
                if (t < NT - 2)
                    asm volatile("s_waitcnt vmcnt(8)" ::: "memory");
                else if (t == NT - 2)
                    asm volatile("s_waitcnt vmcnt(4)" ::: "memory");
            }
            __builtin_amdgcn_sched_barrier(0);
            __builtin_amdgcn_s_barrier();
        }
    }
}

// EPI: 10 = UV merged (u | vT | bS by bx)   2 = gated(PV*u)   3 = out f32(+o_b+x)
template <int EPI, bool SWZ, int NT>
__global__ __launch_bounds__(512, 2) void k8(const unsigned short* __restrict__ A,
                                             const unsigned short* __restrict__ B,
                                             long long strideA, long long strideB,
                                             void* p0, void* p1, void* p2,
                                             const void* p3) {
    constexpr int K = NT * 64;
    __shared__ __align__(16) unsigned short As[2][2][256 * 32];
    __shared__ __align__(16) unsigned short Bs[2][2][256 * 32];
    int tid = threadIdx.x;
    int w = tid >> 6, lane = tid & 63;
    int wr = w >> 2, wc = w & 3;
    int c15 = lane & 15, qq = lane >> 4;
    int gq = qq ^ ((c15 >> 1) & 3);
    int bx = blockIdx.x, by = blockIdx.y, bz = blockIdx.z;
    if constexpr (SWZ) {
        int gx = gridDim.x;
        int nb = gx * gridDim.y;
        int bid = by * gx + bx;
        int s = (bid & 7) * (nb >> 3) + (bid >> 3);
        bx = s % gx;
        by = s / gx;
    }
    const unsigned short* Ab = A + bz * strideA + (long long)by * 256 * K;
    const unsigned short* Bb = B + bz * strideB + (long long)bx * 256 * K;

    f32x4 acc[8][4];
#pragma unroll
    for (int m = 0; m < 8; ++m)
#pragma unroll
        for (int n = 0; n < 4; ++n) acc[m][n] = (f32x4){0.f, 0.f, 0.f, 0.f};

    bool swapped = true;
    if constexpr (EPI == 10) {
        swapped = !(bx >= 6 && bx < 12);
        if (swapped)
            kloop8<true, NT>(Ab, Bb, &As[0][0][0], &Bs[0][0][0], acc, tid, wr, wc, c15, qq, gq);
        else
            kloop8<false, NT>(Ab, Bb, &As[0][0][0], &Bs[0][0][0], acc, tid, wr, wc, c15, qq, gq);
    } else {
        kloop8<true, NT>(Ab, Bb, &As[0][0][0], &Bs[0][0][0], acc, tid, wr, wc, c15, qq, gq);
    }

    if constexpr (EPI == 10) {
        if (swapped) {  // u (bx<6) or bS (bx==12): C^T frags -> row-major stores
            int rowb = by * 256 + wr * 128 + c15;
            int colb = bx * 256 + wc * 64 + (qq << 2);
#pragma unroll
            for (int m = 0; m < 8; ++m) {
#pragma unroll
                for (int n = 0; n < 4; ++n) {
                    int R = rowb + m * 16;
                    int C = colb + n * 16;
                    f32x4 a = acc[m][n];
                    if (C < 1536) {
                        f32x4 bb = *(const f32x4*)((const float*)p3 + C);
                        u16x4 o;
#pragma unroll
                        for (int i = 0; i < 4; ++i) o[i] = f2b(silu(a[i] + bb[i]));
                        *(u16x4*)((unsigned short*)p0 + (long long)R * 1536 + C) = o;
                    } else if (C < 3200) {  // bS
                        f32x4 bb = *(const f32x4*)((const float*)p3 + C);
                        u16x4 o;
#pragma unroll
                        for (int i = 0; i < 4; ++i) o[i] = f2b(silu(a[i] + bb[i]));
                        *(u16x4*)((unsigned short*)p2 + (long long)R * 128 + (C - 3072)) = o;
                    }
                }
            }
        } else {  // vT: thread holds 4 consecutive out-rows at one col
            int rowb = by * 256 + wr * 128 + (qq << 2);
            int colb = bx * 256 + wc * 64 + c15;
#pragma unroll
            for (int m = 0; m < 8; ++m) {
#pragma unroll
                for (int n = 0; n < 4; ++n) {
                    int R = rowb + m * 16;
                    int C = colb + n * 16;  // 1536..3071
                    float bias = ((const float*)p3)[C];
                    f32x4 a = acc[m][n];
                    u16x4 o;
#pragma unroll
                    for (int i = 0; i < 4; ++i) o[i] = f2b(silu(a[i] + bias));
                    int bb2 = R >> 9, mm = R & 511;
                    *(u16x4*)((unsigned short*)p1 +
                              ((long long)bb2 * 1536 + (C - 1536)) * 512 + mm) = o;
                }
            }
        }
    } else if constexpr (EPI == 2) {
        int rowb = by * 256 + wr * 128 + c15;
        int colb = bx * 256 + wc * 64 + (qq << 2);
#pragma unroll
        for (int m = 0; m < 8; ++m) {
#pragma unroll
            for (int n = 0; n < 4; ++n) {
                int R = rowb + m * 16;
                int C = colb + n * 16;
                f32x4 a = acc[m][n];
                long long idx = ((long long)(bz * 512 + R)) * 1536 + C;
                u16x4 uu = *(const u16x4*)((const unsigned short*)p1 + idx);
                u16x4 o;
#pragma unroll
                for (int i = 0; i < 4; ++i) o[i] = f2b(a[i] * b2f(uu[i]));
                *(u16x4*)((unsigned short*)p0 + idx) = o;
            }
        }
    } else {  // EPI == 3
        int rowb = by * 256 + wr * 128 + c15;
        int colb = bx * 256 + wc * 64 + (qq << 2);
#pragma unroll
        for (int m = 0; m < 8; ++m) {
#pragma unroll
            for (int n = 0; n < 4; ++n) {
                int R = rowb + m * 16;
                int C = colb + n * 16;
                f32x4 a = acc[m][n];
                long long idx = (long long)R * 768 + C;
                f32x4 xv = *(const f32x4*)((const float*)p2 + idx);
                f32x4 ob = *(const f32x4*)((const float*)p1 + C);
                f32x4 o;
#pragma unroll
                for (int i = 0; i < 4; ++i) o[i] = a[i] + ob[i] + xv[i];
                *(f32x4*)((float*)p0 + idx) = o;
            }
        }
    }
}

extern "C" void kernel_launch(void* const* d_in, const int* in_sizes, int n_in,
                              void* d_out, int out_size, void* d_ws, size_t ws_size,
                              hipStream_t stream) {
    const float* x     = (const float*)d_in[0];
    const float* ln_g  = (const float*)d_in[1];
    const float* ln_b  = (const float*)d_in[2];
    const float* uv_W  = (const float*)d_in[3];
    const float* uv_b  = (const float*)d_in[4];
    const float* g_qk  = (const float*)d_in[5];
    const float* b_qk  = (const float*)d_in[6];
    const float* w_rel = (const float*)d_in[7];
    const float* o_W   = (const float*)d_in[8];
    const float* o_b   = (const float*)d_in[9];
    float* out = (float*)d_out;

    char* ws = (char*)d_ws;
    size_t off = 0;
    auto alloc = [&](size_t bytes) {
        void* p = ws + off;
        off += (bytes + 255) & ~(size_t)255;
        return p;
    };
    unsigned short* uvWT = (unsigned short*)alloc(3328ll * 768 * 2);  // rows 3200+ = pad
    unsigned short* oWT  = (unsigned short*)alloc(768ll * 1536 * 2);
    unsigned short* xn   = (unsigned short*)alloc(16384ll * 768 * 2);
    unsigned short* u    = (unsigned short*)alloc(16384ll * 1536 * 2);
    unsigned short* vT   = (unsigned short*)alloc(32ll * 1536 * 512 * 2);
    unsigned short* bS   = (unsigned short*)alloc(16384ll * 128 * 2);
    unsigned short* q    = (unsigned short*)alloc(32ll * 512 * 128 * 2);
    unsigned short* k    = (unsigned short*)alloc(32ll * 512 * 128 * 2);
    unsigned short* P     = xn;  // alias: xn dead after UV kernel
    unsigned short* gated = u;   // alias: same-thread read-then-write

    k_convT<<<dim3(100, 24), dim3(32, 8), 0, stream>>>(uv_W, uvWT, 768, 3200);
    k_convT<<<dim3(24, 48), dim3(32, 8), 0, stream>>>(o_W, oWT, 1536, 768);
    k_ln<<<16384, 256, 0, stream>>>(x, ln_g, ln_b, xn);
    // UV merged: u | vT | bS   (N=3328 incl. 128 masked cols; K=768 -> NT=12)
    k8<10, true, 12><<<dim3(13, 64), 512, 0, stream>>>(
        xn, uvWT, 0, 0, (void*)u, (void*)vT, (void*)bS, (const void*)uv_b);
    k_rope<<<16384, 128, 0, stream>>>(bS, g_qk, b_qk, q, k);
    // QK^T -> P
    k_qk<<<dim3(4, 4, 32), 256, 0, stream>>>(q, k, w_rel, P);
    // PV gated by u   (K=512 -> NT=8)
    k8<2, false, 8><<<dim3(6, 2, 32), 512, 0, stream>>>(
        P, vT, 512ll * 512, 1536ll * 512, (void*)gated, (void*)u, nullptr, nullptr);
    // out = gated @ oWT^T + o_b + x   (K=1536 -> NT=24)
    k8<3, true, 24><<<dim3(3, 64), 512, 0, stream>>>(
        gated, oWT, 0, 0, (void*)out, (void*)o_b, (void*)x, nullptr);
}